// Round 13
// baseline (1755.722 us; speedup 1.0000x reference)
//
#include <hip/hip_runtime.h>
#include <hip/hip_bf16.h>

typedef __attribute__((ext_vector_type(8))) short short8;
typedef __attribute__((ext_vector_type(4))) float f32x4;
typedef __attribute__((ext_vector_type(2))) int int2v;

constexpr int BB = 64;    // batch
constexpr int TT = 256;   // time steps
constexpr int II = 512;   // input dim
constexpr int HH = 1024;  // hidden dim

constexpr int NBLK = 256; // 128 blocks per layer: 2 batch-halves x 64 col-groups
constexpr int NTHR = 512; // 8 waves

constexpr int HTILE = (HH / 8) * BB * 8;  // 65536 elems per ring slot
constexpr int XTILE = (II / 8) * BB * 8;  // 32768 elems per t
constexpr int RING = 8;

// workspace layout (bytes)
constexpr size_t OFF_FLAGS = 0;           // 256 flags: [bhalf*128 + jslot*2 + layer]
constexpr size_t OFF_WIH0T = 4096;
constexpr size_t OFF_WHH0T = OFF_WIH0T + (size_t)4096 * 512 * 2;
constexpr size_t OFF_WIH1T = OFF_WHH0T + (size_t)4096 * 1024 * 2;
constexpr size_t OFF_WHH1T = OFF_WIH1T + (size_t)4096 * 1024 * 2;
constexpr size_t OFF_XT    = OFF_WHH1T + (size_t)4096 * 1024 * 2;
constexpr size_t OFF_H0D   = OFF_XT + (size_t)TT * XTILE * 2;        // RING slots
constexpr size_t OFF_H1D   = OFF_H0D + (size_t)RING * HTILE * 2;     // RING slots

__device__ __forceinline__ float sigmoid_(float x) {
  return 1.f / (1.f + __expf(-x));
}
__device__ __forceinline__ float tanh_(float x) {
  float ax = fabsf(x);
  float e = __expf(-2.f * ax);
  float t = (1.f - e) / (1.f + e);
  return copysignf(t, x);
}

__global__ void zero_flags(int* f) { f[blockIdx.x * 256 + threadIdx.x] = 0; }

// src [K][N] fp32 -> dst [N][K] bf16
__global__ void transpose_to_bf16(const float* __restrict__ src,
                                  __hip_bfloat16* __restrict__ dst,
                                  int K, int N) {
  __shared__ float tile[64][65];
  const int n0 = blockIdx.x * 64;
  const int k0 = blockIdx.y * 64;
  const int tx = threadIdx.x & 63;
  const int ty = threadIdx.x >> 6;  // 0..3
#pragma unroll
  for (int i = 0; i < 64; i += 4)
    tile[ty + i][tx] = src[(size_t)(k0 + ty + i) * N + n0 + tx];
  __syncthreads();
#pragma unroll
  for (int i = 0; i < 64; i += 4) {
    const int n = ty + i;
    dst[(size_t)(n0 + n) * K + k0 + tx] = __float2bfloat16(tile[tx][n]);
  }
}

// x [B][T][I] fp32 -> xt [T][I/8][B][8] bf16
__global__ void tile_x(const float* __restrict__ x, __hip_bfloat16* __restrict__ xt) {
  const int t = blockIdx.x;
  const int k = threadIdx.x;  // 512
  __hip_bfloat16* o = xt + (size_t)t * XTILE;
  for (int b = 0; b < BB; ++b) {
    float v = x[((size_t)b * TT + t) * II + k];
    o[(k >> 3) * (BB * 8) + b * 8 + (k & 7)] = __float2bfloat16(v);
  }
}

// h0 [2][B][H] fp32 -> tiled bf16 init states (ring slot 0)
__global__ void init_h(const float* __restrict__ h0, __hip_bfloat16* h0d, __hip_bfloat16* h1d) {
  const int idx = blockIdx.x * 256 + threadIdx.x;  // < 2*BB*HH
  const int l = idx >> 16;
  const int b = (idx >> 10) & 63;
  const int j = idx & 1023;
  __hip_bfloat16 v = __float2bfloat16(h0[idx]);
  __hip_bfloat16* dst = l ? h1d : h0d;
  dst[(j >> 3) * (BB * 8) + b * 8 + (j & 7)] = v;
}

// Balanced wave k-chunk mapping: every wave gets CA "phase-A" chunks
// (x for L0 / lag-certified h0 for L1) and KW-CA "phase-B" chunks (own h).
template <int LAYER>
__device__ __forceinline__ int chunk_kg(int wave, int c) {
  if constexpr (LAYER == 0)
    return (c < 2) ? (wave * 2 + c) * 32 : 512 + (wave * 4 + (c - 2)) * 32;
  else
    return (c < 4) ? (wave * 4 + c) * 32 : 1024 + (wave * 4 + (c - 4)) * 32;
}

template <int KI, int KW, int CA, int LAYER>
__device__ __forceinline__ void scan_impl(
    const __hip_bfloat16* __restrict__ xsrc,  // L0: x_tiled ; L1: unused
    const __hip_bfloat16* __restrict__ WiT,   // [4096][KI]
    const __hip_bfloat16* __restrict__ WhT,   // [4096][HH]
    const float* __restrict__ bias,
    const float* __restrict__ c0_in,
    __hip_bfloat16* h0d, __hip_bfloat16* h1d,
    float* __restrict__ out, int* flags, f32x4 (*part)[2][4][64],
    int bhalf, int jbase, int fslot) {
  const int tid = threadIdx.x;
  const int wave = tid >> 6;
  const int lane = tid & 63;
  const int cc = lane & 15;    // MFMA col / batch-row within tile
  const int lrow = lane >> 4;  // k-chunk sub-select
  constexpr int NB = KW - CA;

  // ---- load W fragments into registers (once, cached loads) ----
  short8 Bf[KW][4];
#pragma unroll
  for (int c = 0; c < KW; ++c) {
    const int kg = chunk_kg<LAYER>(wave, c) + lrow * 8;
#pragma unroll
    for (int g = 0; g < 4; ++g) {
      const int gcol = g * HH + jbase + cc;
      const __hip_bfloat16* p;
      if (kg < KI) p = WiT + (size_t)gcol * KI + kg;
      else         p = WhT + (size_t)gcol * HH + (kg - KI);
      Bf[c][g] = *(const short8*)p;
    }
  }

  // ---- epilogue constants: thread handles cell (eb, ej) ----
  const int ejl = tid & 15;            // j within tile
  const int ebl = tid >> 4;            // 0..31 batch row within half
  const int ej = jbase + ejl;
  const int eb = bhalf * 32 + ebl;
  const int pm = ebl >> 4, psub = (ebl >> 2) & 3, pr = ebl & 3;
  // per-thread base offset (floats) into part[8][2][4][64] f32x4 viewed flat
  const int rdbase = pm * 1024 + (psub * 16 + ejl) * 4 + pr;
  const float bi = bias[ej];
  const float bf_ = bias[HH + ej];
  const float bg = bias[2 * HH + ej];
  const float bo = bias[3 * HH + ej];
  float cst = c0_in[(size_t)LAYER * BB * HH + (size_t)eb * HH + ej];

  // poll source: lane reads (L0,L1) flag pair of jslot=lane in our bhalf
  const int* fpair = flags + bhalf * 128 + lane * 2;

  for (int tau = 0; tau < TT + 2; ++tau) {
    const bool active = (LAYER == 0) ? (tau < TT) : (tau >= 2);
    const int p = (LAYER == 0) ? tau : tau - 2;

    // ---- cache hygiene at loop TOP, before any load is outstanding ----
    if (tau > 0 && wave == 0)
      __builtin_amdgcn_fence(__ATOMIC_ACQUIRE, "agent");

    const __hip_bfloat16* px;
    const __hip_bfloat16* ph;
    __hip_bfloat16* hout;
    if constexpr (LAYER == 0) {
      px = xsrc + (size_t)p * XTILE;
      ph = h0d + (size_t)(p & (RING - 1)) * HTILE;          // ver p (own group)
      hout = h0d + (size_t)((p + 1) & (RING - 1)) * HTILE;  // ver p+1
    } else {
      px = h0d + (size_t)((p + 1) & (RING - 1)) * HTILE;    // h0 ver p+1 (lag-2 certified)
      ph = h1d + (size_t)(p & (RING - 1)) * HTILE;          // ver p (own group)
      hout = h1d + (size_t)((p + 1) & (RING - 1)) * HTILE;  // ver p+1
    }

    f32x4 acc[2][4] = {};
    short8 abufA[CA][2];   // phase-A staging (must survive until consumed)
    short8 abufB[NB][2];   // phase-B staging (separate: wave 0 defers A-consume)

    auto issue_chunk = [&](int c, short8* dst) {
      const int kg = chunk_kg<LAYER>(wave, c);
      const __hip_bfloat16* ab;
      int kc;
      if (kg < KI) { ab = px; kc = (kg >> 3) + lrow; }
      else         { ab = ph; kc = ((kg - KI) >> 3) + lrow; }
#pragma unroll
      for (int m = 0; m < 2; ++m) {
        const __hip_bfloat16* ptr =
            ab + (size_t)kc * (BB * 8) + (size_t)(bhalf * 32 + m * 16 + cc) * 8;
        asm volatile("global_load_dwordx4 %0, %1, off" : "=v"(dst[m]) : "v"(ptr));
      }
    };

    // ---- PHASE A: issue barrier-independent loads (x / lag-2 h0) ----
    if (active) {
#pragma unroll
      for (int c = 0; c < CA; ++c) issue_chunk(c, abufA[c]);
    }

    // ---- group barrier: 64 same-(layer,bhalf) blocks; wave 0 polls ----
    // L0 needs own-group >= tau and (writer gate, ring-8) L1 >= tau-5.
    // L1 needs own-group >= tau and L0 >= tau.
    if (tau > 0 && wave == 0) {
      for (;;) {
        int2v v;
        asm volatile("global_load_dwordx2 %0, %1, off sc0 sc1\n\t"
                     "s_waitcnt vmcnt(0)"
                     : "=v"(v) : "v"(fpair) : "memory");
        int mn;
        if constexpr (LAYER == 0) mn = min(v.x, v.y + 5);
        else                      mn = min(v.x, v.y);
        if (__all(mn >= tau)) break;
        __builtin_amdgcn_s_sleep(2);
      }
    }

    // ---- PHASE A consume on waves 1-7 (overlaps wave-0 poll); wave 0
    //      defers its A-consume to post-sync to keep the poll path short ----
    if (active && wave != 0) {
      asm volatile("s_waitcnt vmcnt(0)" ::: "memory");
      __builtin_amdgcn_sched_barrier(0);
#pragma unroll
      for (int c = 0; c < CA; ++c)
#pragma unroll
        for (int m = 0; m < 2; ++m)
#pragma unroll
          for (int g = 0; g < 4; ++g)
            acc[m][g] = __builtin_amdgcn_mfma_f32_16x16x32_bf16(
                abufA[c][m], Bf[c][g], acc[m][g], 0, 0, 0);
    }

    __syncthreads();

    if (active) {
      // ---- PHASE B: own-group h chunks, pipelined (separate registers) ----
#pragma unroll
      for (int c = 0; c < NB; ++c) issue_chunk(CA + c, abufB[c]);

      if (wave == 0) {
        // deferred A-consume: vmcnt(8) leaves the 8 B-loads in flight,
        // retires all (older) A-loads. abufA intact (separate from abufB).
        asm volatile("s_waitcnt vmcnt(8)" ::: "memory");
        __builtin_amdgcn_sched_barrier(0);
#pragma unroll
        for (int c = 0; c < CA; ++c)
#pragma unroll
          for (int m = 0; m < 2; ++m)
#pragma unroll
            for (int g = 0; g < 4; ++g)
              acc[m][g] = __builtin_amdgcn_mfma_f32_16x16x32_bf16(
                  abufA[c][m], Bf[c][g], acc[m][g], 0, 0, 0);
      }

#pragma unroll
      for (int c = 0; c < NB; ++c) {
        const int vm = 2 * (NB - 1 - c);
        if (vm == 6)      asm volatile("s_waitcnt vmcnt(6)" ::: "memory");
        else if (vm == 4) asm volatile("s_waitcnt vmcnt(4)" ::: "memory");
        else if (vm == 2) asm volatile("s_waitcnt vmcnt(2)" ::: "memory");
        else              asm volatile("s_waitcnt vmcnt(0)" ::: "memory");
        __builtin_amdgcn_sched_barrier(0);
#pragma unroll
        for (int m = 0; m < 2; ++m)
#pragma unroll
          for (int g = 0; g < 4; ++g)
            acc[m][g] = __builtin_amdgcn_mfma_f32_16x16x32_bf16(
                abufB[c][m], Bf[CA + c][g], acc[m][g], 0, 0, 0);
      }

      // ---- stage k-partials to LDS (b128, lane-consecutive) ----
#pragma unroll
      for (int m = 0; m < 2; ++m)
#pragma unroll
        for (int g = 0; g < 4; ++g)
          part[wave][m][g][lane] = acc[m][g];
      __syncthreads();

      // ---- reduce + LSTM cell, spread over all 512 threads ----
      const float* pp = (const float*)part;
      float s0 = 0.f, s1 = 0.f, s2 = 0.f, s3 = 0.f;
#pragma unroll
      for (int w = 0; w < 8; ++w) {
        s0 += pp[w * 2048 + 0 * 256 + rdbase];
        s1 += pp[w * 2048 + 1 * 256 + rdbase];
        s2 += pp[w * 2048 + 2 * 256 + rdbase];
        s3 += pp[w * 2048 + 3 * 256 + rdbase];
      }
      float iv = sigmoid_(s0 + bi);
      float fv = sigmoid_(s1 + bf_);
      float gv = tanh_(s2 + bg);
      float ov = sigmoid_(s3 + bo);
      float cn = fv * cst + iv * gv;
      cst = cn;
      float hv = ov * tanh_(cn);
      // pack 2 adjacent bf16 cols -> one dword, write-through to LLC
      __hip_bfloat16 hb = __float2bfloat16(hv);
      unsigned short hu = *reinterpret_cast<unsigned short*>(&hb);
      unsigned pu = (unsigned)__shfl_xor((int)hu, 1);
      if ((tid & 1) == 0) {
        uint32_t packed = (uint32_t)hu | ((pu & 0xffffu) << 16);
        uint32_t* hq = (uint32_t*)hout;
        __hip_atomic_store(hq + (ej >> 3) * 256 + eb * 4 + ((ej & 7) >> 1), packed,
                           __ATOMIC_RELAXED, __HIP_MEMORY_SCOPE_AGENT);
      }
      // drain h stores, rendezvous, publish, THEN issue out[] stores
      asm volatile("s_waitcnt vmcnt(0)" ::: "memory");
      __syncthreads();
      if (tid == 0)
        __hip_atomic_store(&flags[fslot], tau + 1, __ATOMIC_RELAXED, __HIP_MEMORY_SCOPE_AGENT);
      if constexpr (LAYER == 1)
        out[((size_t)eb * TT + p) * HH + ej] = hv;
      if (p == TT - 1) {
        out[(size_t)BB * TT * HH + (size_t)LAYER * BB * HH + (size_t)eb * HH + ej] = hv;
        out[(size_t)BB * TT * HH + (size_t)2 * BB * HH + (size_t)LAYER * BB * HH + (size_t)eb * HH + ej] = cn;
      }
      // loop-end drain: out[] store acks retire here, off next window's chain
      asm volatile("s_waitcnt vmcnt(0)" ::: "memory");
    } else {
      if (tid == 0)
        __hip_atomic_store(&flags[fslot], tau + 1, __ATOMIC_RELAXED, __HIP_MEMORY_SCOPE_AGENT);
    }
  }
}

__global__ __launch_bounds__(NTHR, 2) void lstm_scan(
    const __hip_bfloat16* __restrict__ xt,
    const __hip_bfloat16* __restrict__ Wih0T, const __hip_bfloat16* __restrict__ Whh0T,
    const __hip_bfloat16* __restrict__ Wih1T, const __hip_bfloat16* __restrict__ Whh1T,
    const float* __restrict__ b0, const float* __restrict__ b1,
    const float* __restrict__ c0_in,
    __hip_bfloat16* h0d, __hip_bfloat16* h1d,
    float* __restrict__ out, int* flags) {
  __shared__ f32x4 part[8][2][4][64];  // 32 KiB
  const int blk = blockIdx.x;
  const int jslot = blk & 63;
  const int bhalf = (blk >> 6) & 1;
  const int layer = blk >> 7;
  const int jbase = jslot * 16;
  // flag slot: interleaved (L0,L1) pairs per jslot within each bhalf region
  const int fslot = bhalf * 128 + jslot * 2 + layer;
  if (layer == 0)
    scan_impl<512, 6, 2, 0>(xt, Wih0T, Whh0T, b0, c0_in, h0d, h1d, out, flags, part, bhalf, jbase, fslot);
  else
    scan_impl<1024, 8, 4, 1>(nullptr, Wih1T, Whh1T, b1, c0_in, h0d, h1d, out, flags, part, bhalf, jbase, fslot);
}

extern "C" void kernel_launch(void* const* d_in, const int* in_sizes, int n_in,
                              void* d_out, int out_size, void* d_ws, size_t ws_size,
                              hipStream_t stream) {
  (void)in_sizes; (void)n_in; (void)out_size; (void)ws_size;
  const float* x    = (const float*)d_in[0];
  const float* h0   = (const float*)d_in[1];
  const float* c0   = (const float*)d_in[2];
  const float* Wih0 = (const float*)d_in[3];
  const float* Whh0 = (const float*)d_in[4];
  const float* b0   = (const float*)d_in[5];
  const float* Wih1 = (const float*)d_in[6];
  const float* Whh1 = (const float*)d_in[7];
  const float* b1   = (const float*)d_in[8];
  float* out = (float*)d_out;
  char* ws = (char*)d_ws;

  int* flags = (int*)(ws + OFF_FLAGS);
  __hip_bfloat16* wih0t = (__hip_bfloat16*)(ws + OFF_WIH0T);
  __hip_bfloat16* whh0t = (__hip_bfloat16*)(ws + OFF_WHH0T);
  __hip_bfloat16* wih1t = (__hip_bfloat16*)(ws + OFF_WIH1T);
  __hip_bfloat16* whh1t = (__hip_bfloat16*)(ws + OFF_WHH1T);
  __hip_bfloat16* xtl   = (__hip_bfloat16*)(ws + OFF_XT);
  __hip_bfloat16* h0d   = (__hip_bfloat16*)(ws + OFF_H0D);
  __hip_bfloat16* h1d   = (__hip_bfloat16*)(ws + OFF_H1D);

  zero_flags<<<2, 256, 0, stream>>>(flags);
  transpose_to_bf16<<<dim3(64, 8),  256, 0, stream>>>(Wih0, wih0t, 512, 4096);
  transpose_to_bf16<<<dim3(64, 16), 256, 0, stream>>>(Whh0, whh0t, 1024, 4096);
  transpose_to_bf16<<<dim3(64, 16), 256, 0, stream>>>(Wih1, wih1t, 1024, 4096);
  transpose_to_bf16<<<dim3(64, 16), 256, 0, stream>>>(Whh1, whh1t, 1024, 4096);
  tile_x<<<TT, 512, 0, stream>>>(x, xtl);
  init_h<<<512, 256, 0, stream>>>(h0, h0d, h1d);
  lstm_scan<<<NBLK, NTHR, 0, stream>>>(xtl, wih0t, whh0t, wih1t, whh1t,
                                       b0, b1, c0, h0d, h1d, out, flags);
}

// Round 14
// 1513.617 us; speedup vs baseline: 1.1600x; 1.1600x over previous
//
#include <hip/hip_runtime.h>
#include <hip/hip_bf16.h>

typedef __attribute__((ext_vector_type(8))) short short8;
typedef __attribute__((ext_vector_type(4))) float f32x4;
typedef __attribute__((ext_vector_type(2))) int int2v;

constexpr int BB = 64;    // batch
constexpr int TT = 256;   // time steps
constexpr int II = 512;   // input dim
constexpr int HH = 1024;  // hidden dim

constexpr int NBLK = 256; // 128 blocks per layer: 2 batch-halves x 64 col-groups
constexpr int NTHR = 512; // 8 waves

constexpr int HTILE = (HH / 8) * BB * 8;  // 65536 elems per ring slot
constexpr int XTILE = (II / 8) * BB * 8;  // 32768 elems per t
constexpr int RING = 8;

// workspace layout (bytes)
constexpr size_t OFF_FLAGS = 0;           // 256 flags, grouped by bhalf (+spare)
constexpr size_t OFF_WIH0T = 4096;
constexpr size_t OFF_WHH0T = OFF_WIH0T + (size_t)4096 * 512 * 2;
constexpr size_t OFF_WIH1T = OFF_WHH0T + (size_t)4096 * 1024 * 2;
constexpr size_t OFF_WHH1T = OFF_WIH1T + (size_t)4096 * 1024 * 2;
constexpr size_t OFF_XT    = OFF_WHH1T + (size_t)4096 * 1024 * 2;
constexpr size_t OFF_H0D   = OFF_XT + (size_t)TT * XTILE * 2;        // RING slots
constexpr size_t OFF_H1D   = OFF_H0D + (size_t)RING * HTILE * 2;     // RING slots

__device__ __forceinline__ float sigmoid_(float x) {
  return 1.f / (1.f + __expf(-x));
}
__device__ __forceinline__ float tanh_(float x) {
  float ax = fabsf(x);
  float e = __expf(-2.f * ax);
  float t = (1.f - e) / (1.f + e);
  return copysignf(t, x);
}

__global__ void zero_flags(int* f) { f[blockIdx.x * 256 + threadIdx.x] = 0; }

// src [K][N] fp32 -> dst [N][K] bf16
__global__ void transpose_to_bf16(const float* __restrict__ src,
                                  __hip_bfloat16* __restrict__ dst,
                                  int K, int N) {
  __shared__ float tile[64][65];
  const int n0 = blockIdx.x * 64;
  const int k0 = blockIdx.y * 64;
  const int tx = threadIdx.x & 63;
  const int ty = threadIdx.x >> 6;  // 0..3
#pragma unroll
  for (int i = 0; i < 64; i += 4)
    tile[ty + i][tx] = src[(size_t)(k0 + ty + i) * N + n0 + tx];
  __syncthreads();
#pragma unroll
  for (int i = 0; i < 64; i += 4) {
    const int n = ty + i;
    dst[(size_t)(n0 + n) * K + k0 + tx] = __float2bfloat16(tile[tx][n]);
  }
}

// x [B][T][I] fp32 -> xt [T][I/8][B][8] bf16
__global__ void tile_x(const float* __restrict__ x, __hip_bfloat16* __restrict__ xt) {
  const int t = blockIdx.x;
  const int k = threadIdx.x;  // 512
  __hip_bfloat16* o = xt + (size_t)t * XTILE;
  for (int b = 0; b < BB; ++b) {
    float v = x[((size_t)b * TT + t) * II + k];
    o[(k >> 3) * (BB * 8) + b * 8 + (k & 7)] = __float2bfloat16(v);
  }
}

// h0 [2][B][H] fp32 -> tiled bf16 init states (ring slot 0)
__global__ void init_h(const float* __restrict__ h0, __hip_bfloat16* h0d, __hip_bfloat16* h1d) {
  const int idx = blockIdx.x * 256 + threadIdx.x;  // < 2*BB*HH
  const int l = idx >> 16;
  const int b = (idx >> 10) & 63;
  const int j = idx & 1023;
  __hip_bfloat16 v = __float2bfloat16(h0[idx]);
  __hip_bfloat16* dst = l ? h1d : h0d;
  dst[(j >> 3) * (BB * 8) + b * 8 + (j & 7)] = v;
}

// Balanced wave k-chunk mapping: every wave gets CA "phase-A" chunks
// (x for L0 / lag-certified h0 for L1) and KW-CA "phase-B" chunks (own h).
template <int LAYER>
__device__ __forceinline__ int chunk_kg(int wave, int c) {
  if constexpr (LAYER == 0)
    return (c < 2) ? (wave * 2 + c) * 32 : 512 + (wave * 4 + (c - 2)) * 32;
  else
    return (c < 4) ? (wave * 4 + c) * 32 : 1024 + (wave * 4 + (c - 4)) * 32;
}

template <int KI, int KW, int CA, int LAYER>
__device__ __forceinline__ void scan_impl(
    const __hip_bfloat16* __restrict__ xsrc,  // L0: x_tiled ; L1: unused
    const __hip_bfloat16* __restrict__ WiT,   // [4096][KI]
    const __hip_bfloat16* __restrict__ WhT,   // [4096][HH]
    const float* __restrict__ bias,
    const float* __restrict__ c0_in,
    __hip_bfloat16* h0d, __hip_bfloat16* h1d,
    float* __restrict__ out, int* flags, f32x4 (*part)[2][4][64],
    int bhalf, int jbase, int fslot) {
  const int tid = threadIdx.x;
  const int wave = tid >> 6;
  const int lane = tid & 63;
  const int cc = lane & 15;    // MFMA col / batch-row within tile
  const int lrow = lane >> 4;  // k-chunk sub-select
  constexpr int NB = KW - CA;

  // ---- load W fragments into registers (once, cached loads) ----
  short8 Bf[KW][4];
#pragma unroll
  for (int c = 0; c < KW; ++c) {
    const int kg = chunk_kg<LAYER>(wave, c) + lrow * 8;
#pragma unroll
    for (int g = 0; g < 4; ++g) {
      const int gcol = g * HH + jbase + cc;
      const __hip_bfloat16* p;
      if (kg < KI) p = WiT + (size_t)gcol * KI + kg;
      else         p = WhT + (size_t)gcol * HH + (kg - KI);
      Bf[c][g] = *(const short8*)p;
    }
  }

  // ---- epilogue constants: thread handles cell (eb, ej) ----
  const int ejl = tid & 15;            // j within tile
  const int ebl = tid >> 4;            // 0..31 batch row within half
  const int ej = jbase + ejl;
  const int eb = bhalf * 32 + ebl;
  const int pm = ebl >> 4, psub = (ebl >> 2) & 3, pr = ebl & 3;
  // per-thread base offset (floats) into part[8][2][4][64] f32x4 viewed flat
  const int rdbase = pm * 1024 + (psub * 16 + ejl) * 4 + pr;
  const float bi = bias[ej];
  const float bf_ = bias[HH + ej];
  const float bg = bias[2 * HH + ej];
  const float bo = bias[3 * HH + ej];
  float cst = c0_in[(size_t)LAYER * BB * HH + (size_t)eb * HH + ej];

  // poll source: group(bhalf) flags are contiguous [bhalf*128, +128);
  // lane reads 2 flags via one dwordx2.
  const int* fpair = flags + bhalf * 128 + lane * 2;

  for (int tau = 0; tau < TT + 2; ++tau) {
    const bool active = (LAYER == 0) ? (tau < TT) : (tau >= 2);
    const int p = (LAYER == 0) ? tau : tau - 2;

    const __hip_bfloat16* px;
    const __hip_bfloat16* ph;
    __hip_bfloat16* hout;
    if constexpr (LAYER == 0) {
      px = xsrc + (size_t)p * XTILE;
      ph = h0d + (size_t)(p & (RING - 1)) * HTILE;          // ver p (own group)
      hout = h0d + (size_t)((p + 1) & (RING - 1)) * HTILE;  // ver p+1
    } else {
      px = h0d + (size_t)((p + 1) & (RING - 1)) * HTILE;    // h0 ver p+1 (lag-2 certified)
      ph = h1d + (size_t)(p & (RING - 1)) * HTILE;          // ver p (own group)
      hout = h1d + (size_t)((p + 1) & (RING - 1)) * HTILE;  // ver p+1
    }

    f32x4 acc[2][4] = {};
    short8 abuf[4][2];

    auto issue_chunk = [&](int c, short8* dst) {
      const int kg = chunk_kg<LAYER>(wave, c);
      const __hip_bfloat16* ab;
      int kc;
      if (kg < KI) { ab = px; kc = (kg >> 3) + lrow; }
      else         { ab = ph; kc = ((kg - KI) >> 3) + lrow; }
#pragma unroll
      for (int m = 0; m < 2; ++m) {
        const __hip_bfloat16* ptr =
            ab + (size_t)kc * (BB * 8) + (size_t)(bhalf * 32 + m * 16 + cc) * 8;
        asm volatile("global_load_dwordx4 %0, %1, off" : "=v"(dst[m]) : "v"(ptr));
      }
    };

    // ---- PHASE A: issue barrier-independent loads (x / lag-2 h0) ----
    if (active) {
#pragma unroll
      for (int c = 0; c < CA; ++c) issue_chunk(c, abuf[c]);
    }

    // ---- group barrier (128 blocks of our bhalf): wave 0 polls ----
    if (tau > 0 && wave == 0) {
      for (;;) {
        int2v v;
        asm volatile("global_load_dwordx2 %0, %1, off sc0 sc1\n\t"
                     "s_waitcnt vmcnt(0)"
                     : "=v"(v) : "v"(fpair) : "memory");
        int mn = min(v.x, v.y);
        if (__all(mn >= tau)) break;
        __builtin_amdgcn_s_sleep(1);
      }
    }

    // ---- PHASE A consume: MFMAs on phase-A chunks (overlaps wave-0 poll) ----
    if (active) {
      asm volatile("s_waitcnt vmcnt(0)" ::: "memory");
      __builtin_amdgcn_sched_barrier(0);
#pragma unroll
      for (int c = 0; c < CA; ++c)
#pragma unroll
        for (int m = 0; m < 2; ++m)
#pragma unroll
          for (int g = 0; g < 4; ++g)
            acc[m][g] = __builtin_amdgcn_mfma_f32_16x16x32_bf16(
                abuf[c][m], Bf[c][g], acc[m][g], 0, 0, 0);
    }

    // ---- acquire fence (wave 0 only, per block) then single rendezvous.
    // Concurrent inv vs other waves' certified-fresh A-loads is safe: either
    // L2-hit (fresh) or LLC refill (fresh). B-loads issue strictly post-sync.
    if (tau > 0 && wave == 0)
      __builtin_amdgcn_fence(__ATOMIC_ACQUIRE, "agent");
    __syncthreads();

    if (active) {
      // ---- PHASE B: own-group h chunks, pipelined ----
#pragma unroll
      for (int c = 0; c < NB; ++c) issue_chunk(CA + c, abuf[c]);
#pragma unroll
      for (int c = 0; c < NB; ++c) {
        const int vm = 2 * (NB - 1 - c);
        if (vm == 6)      asm volatile("s_waitcnt vmcnt(6)" ::: "memory");
        else if (vm == 4) asm volatile("s_waitcnt vmcnt(4)" ::: "memory");
        else if (vm == 2) asm volatile("s_waitcnt vmcnt(2)" ::: "memory");
        else              asm volatile("s_waitcnt vmcnt(0)" ::: "memory");
        __builtin_amdgcn_sched_barrier(0);
#pragma unroll
        for (int m = 0; m < 2; ++m)
#pragma unroll
          for (int g = 0; g < 4; ++g)
            acc[m][g] = __builtin_amdgcn_mfma_f32_16x16x32_bf16(
                abuf[c][m], Bf[CA + c][g], acc[m][g], 0, 0, 0);
      }

      // ---- stage k-partials to LDS (b128, lane-consecutive) ----
#pragma unroll
      for (int m = 0; m < 2; ++m)
#pragma unroll
        for (int g = 0; g < 4; ++g)
          part[wave][m][g][lane] = acc[m][g];
      __syncthreads();

      // ---- reduce + LSTM cell, spread over all 512 threads ----
      const float* pp = (const float*)part;
      float s0 = 0.f, s1 = 0.f, s2 = 0.f, s3 = 0.f;
#pragma unroll
      for (int w = 0; w < 8; ++w) {
        s0 += pp[w * 2048 + 0 * 256 + rdbase];
        s1 += pp[w * 2048 + 1 * 256 + rdbase];
        s2 += pp[w * 2048 + 2 * 256 + rdbase];
        s3 += pp[w * 2048 + 3 * 256 + rdbase];
      }
      float iv = sigmoid_(s0 + bi);
      float fv = sigmoid_(s1 + bf_);
      float gv = tanh_(s2 + bg);
      float ov = sigmoid_(s3 + bo);
      float cn = fv * cst + iv * gv;
      cst = cn;
      float hv = ov * tanh_(cn);
      // pack 2 adjacent bf16 cols -> one dword, write-through to LLC
      __hip_bfloat16 hb = __float2bfloat16(hv);
      unsigned short hu = *reinterpret_cast<unsigned short*>(&hb);
      unsigned pu = (unsigned)__shfl_xor((int)hu, 1);
      if ((tid & 1) == 0) {
        uint32_t packed = (uint32_t)hu | ((pu & 0xffffu) << 16);
        uint32_t* hq = (uint32_t*)hout;
        __hip_atomic_store(hq + (ej >> 3) * 256 + eb * 4 + ((ej & 7) >> 1), packed,
                           __ATOMIC_RELAXED, __HIP_MEMORY_SCOPE_AGENT);
      }
      // drain h stores, rendezvous, publish, THEN issue out[] stores
      asm volatile("s_waitcnt vmcnt(0)" ::: "memory");
      __syncthreads();
      if (tid == 0)
        __hip_atomic_store(&flags[fslot], tau + 1, __ATOMIC_RELAXED, __HIP_MEMORY_SCOPE_AGENT);
      if constexpr (LAYER == 1)
        out[((size_t)eb * TT + p) * HH + ej] = hv;
      if (p == TT - 1) {
        out[(size_t)BB * TT * HH + (size_t)LAYER * BB * HH + (size_t)eb * HH + ej] = hv;
        out[(size_t)BB * TT * HH + (size_t)2 * BB * HH + (size_t)LAYER * BB * HH + (size_t)eb * HH + ej] = cn;
      }
      // loop-end drain: out[] store acks retire in the shadow of the next
      // poll instead of stalling next window's first vmcnt(0).
      asm volatile("s_waitcnt vmcnt(0)" ::: "memory");
    } else {
      if (tid == 0)
        __hip_atomic_store(&flags[fslot], tau + 1, __ATOMIC_RELAXED, __HIP_MEMORY_SCOPE_AGENT);
    }
  }
}

__global__ __launch_bounds__(NTHR, 2) void lstm_scan(
    const __hip_bfloat16* __restrict__ xt,
    const __hip_bfloat16* __restrict__ Wih0T, const __hip_bfloat16* __restrict__ Whh0T,
    const __hip_bfloat16* __restrict__ Wih1T, const __hip_bfloat16* __restrict__ Whh1T,
    const float* __restrict__ b0, const float* __restrict__ b1,
    const float* __restrict__ c0_in,
    __hip_bfloat16* h0d, __hip_bfloat16* h1d,
    float* __restrict__ out, int* flags) {
  __shared__ f32x4 part[8][2][4][64];  // 32 KiB
  const int blk = blockIdx.x;
  const int jslot = blk & 63;
  const int bhalf = (blk >> 6) & 1;
  const int layer = blk >> 7;
  const int jbase = jslot * 16;
  // group(bhalf)-contiguous flag slot: [bhalf*128 + layer*64 + jslot]
  const int fslot = bhalf * 128 + layer * 64 + jslot;
  if (layer == 0)
    scan_impl<512, 6, 2, 0>(xt, Wih0T, Whh0T, b0, c0_in, h0d, h1d, out, flags, part, bhalf, jbase, fslot);
  else
    scan_impl<1024, 8, 4, 1>(nullptr, Wih1T, Whh1T, b1, c0_in, h0d, h1d, out, flags, part, bhalf, jbase, fslot);
}

extern "C" void kernel_launch(void* const* d_in, const int* in_sizes, int n_in,
                              void* d_out, int out_size, void* d_ws, size_t ws_size,
                              hipStream_t stream) {
  (void)in_sizes; (void)n_in; (void)out_size; (void)ws_size;
  const float* x    = (const float*)d_in[0];
  const float* h0   = (const float*)d_in[1];
  const float* c0   = (const float*)d_in[2];
  const float* Wih0 = (const float*)d_in[3];
  const float* Whh0 = (const float*)d_in[4];
  const float* b0   = (const float*)d_in[5];
  const float* Wih1 = (const float*)d_in[6];
  const float* Whh1 = (const float*)d_in[7];
  const float* b1   = (const float*)d_in[8];
  float* out = (float*)d_out;
  char* ws = (char*)d_ws;

  int* flags = (int*)(ws + OFF_FLAGS);
  __hip_bfloat16* wih0t = (__hip_bfloat16*)(ws + OFF_WIH0T);
  __hip_bfloat16* whh0t = (__hip_bfloat16*)(ws + OFF_WHH0T);
  __hip_bfloat16* wih1t = (__hip_bfloat16*)(ws + OFF_WIH1T);
  __hip_bfloat16* whh1t = (__hip_bfloat16*)(ws + OFF_WHH1T);
  __hip_bfloat16* xtl   = (__hip_bfloat16*)(ws + OFF_XT);
  __hip_bfloat16* h0d   = (__hip_bfloat16*)(ws + OFF_H0D);
  __hip_bfloat16* h1d   = (__hip_bfloat16*)(ws + OFF_H1D);

  zero_flags<<<2, 256, 0, stream>>>(flags);
  transpose_to_bf16<<<dim3(64, 8),  256, 0, stream>>>(Wih0, wih0t, 512, 4096);
  transpose_to_bf16<<<dim3(64, 16), 256, 0, stream>>>(Whh0, whh0t, 1024, 4096);
  transpose_to_bf16<<<dim3(64, 16), 256, 0, stream>>>(Wih1, wih1t, 1024, 4096);
  transpose_to_bf16<<<dim3(64, 16), 256, 0, stream>>>(Whh1, whh1t, 1024, 4096);
  tile_x<<<TT, 512, 0, stream>>>(x, xtl);
  init_h<<<512, 256, 0, stream>>>(h0, h0d, h1d);
  lstm_scan<<<NBLK, NTHR, 0, stream>>>(xtl, wih0t, whh0t, wih1t, whh1t,
                                       b0, b1, c0, h0d, h1d, out, flags);
}